// Round 5
// baseline (495.346 us; speedup 1.0000x reference)
//
#include <hip/hip_runtime.h>
#include <hip/hip_bf16.h>

#define B_ 32
#define S_ 2048
#define D_ 512

// ---------------------------------------------------------------------------
// workspace layout (bytes).
// ---------------------------------------------------------------------------
#define WS_GATE  0                           // 32*2048*4 = 262144
#define WS_FLAG  262144                      // 16 B (padded to 4 KB)
#define WS_SW    266240                      // shareW tiled: 64 tiles * 8192 B
#define WS_LW    (WS_SW + 64 * 8192)         // langsW tiled: 512 tiles
#define WS_W1    (WS_LW + 512 * 8192)        // gate W1 tiled: 512 tiles
#define WS_B1F   (WS_W1 + 512 * 8192)        // b1 as f32
#define WS_W2F   (WS_B1F + 16384)            // W2 as f32
#define WS_B2F   (WS_W2F + 16384)            // b2 as f32 (padded)
#define WS_XB    (WS_B2F + 4096)             // x as bf16 row-major: 64 MB
#define WS_OXB   (WS_XB + 67108864LL)        // old_x as bf16 row-major: 64 MB
#define WS_NEED  (WS_OXB + 67108864LL)       // ~143.4 MB

typedef __attribute__((ext_vector_type(8))) short bf16x8;   // 8 bf16 = 4 VGPRs
typedef __attribute__((ext_vector_type(4))) float f32x4;    // MFMA 16x16 accumulator
typedef unsigned short ushort_t;

__device__ __forceinline__ float b2f(ushort_t u) {
  union { unsigned int i; float f; } v; v.i = ((unsigned int)u) << 16; return v.f;
}
__device__ __forceinline__ ushort_t f2b(float f) {   // RTNE fp32 -> bf16 bits
  union { float f; unsigned int i; } v; v.f = f;
  return (ushort_t)((v.i + 0x7FFFu + ((v.i >> 16) & 1u)) >> 16);
}

__device__ __forceinline__ f32x4 mfma16(bf16x8 a, bf16x8 b, f32x4 c) {
  return __builtin_amdgcn_mfma_f32_16x16x32_bf16(a, b, c, 0, 0, 0);
}

// global -> LDS direct DMA, 16 B per lane. gptr per-lane, lptr wave-uniform.
__device__ __forceinline__ void gload16(const void* g, void* l) {
  __builtin_amdgcn_global_load_lds(
      (const __attribute__((address_space(1))) unsigned int*)g,
      (__attribute__((address_space(3))) unsigned int*)l, 16, 0, 0);
}

// ---------------------------------------------------------------------------
// dtype detection: 1 = bf16 storage, 0 = fp32 storage.
// ---------------------------------------------------------------------------
__global__ void detect_kernel(const unsigned int* __restrict__ w, int* __restrict__ flag) {
  __shared__ int cnt;
  if (threadIdx.x == 0) cnt = 0;
  __syncthreads();
  int c = 0;
  #pragma unroll
  for (int i = 0; i < 4; ++i) {
    unsigned int v = w[threadIdx.x + i * 256];
    unsigned int e = (v >> 7) & 0xFFu;
    if (e >= 110u && e <= 140u) ++c;
  }
  atomicAdd(&cnt, c);
  __syncthreads();
  if (threadIdx.x == 0) flag[0] = (cnt > 512) ? 1 : 0;
}

// read one 8-element (K=32) MFMA fragment from a row-stride-32 swizzled tile.
__device__ __forceinline__ bf16x8 read_frag(const ushort_t* tile, int row, int quad) {
  int g = quad ^ ((row >> 1) & 3);
  return *(const bf16x8*)(tile + row * 32 + g * 8);
}

// ---------------------------------------------------------------------------
// [128 x 32] tile staging helpers (used by convert pass + tier-B fallback).
// ---------------------------------------------------------------------------
template <int DT> struct TR16 { float4 f[4]; bf16x8 h[2]; };

template <int DT>
__device__ __forceinline__ void t16_load(const void* gv, size_t base, int tid, TR16<DT>& t) {
  const int row = tid >> 1, half = tid & 1;
  const size_t off = base + (size_t)row * D_ + half * 16;
  if constexpr (DT == 0) {
    const float4* s = (const float4*)((const float*)gv + off);
    t.f[0] = s[0]; t.f[1] = s[1]; t.f[2] = s[2]; t.f[3] = s[3];
  } else {
    const bf16x8* s = (const bf16x8*)((const ushort_t*)gv + off);
    t.h[0] = s[0]; t.h[1] = s[1];
  }
}
template <int DT>
__device__ __forceinline__ void t16_store(ushort_t* tile, int tid, const TR16<DT>& t) {
  const int row = tid >> 1, half = tid & 1;
  bf16x8 ch0, ch1;
  if constexpr (DT == 0) {
    ushort_t u[16];
    u[0]  = f2b(t.f[0].x); u[1]  = f2b(t.f[0].y); u[2]  = f2b(t.f[0].z); u[3]  = f2b(t.f[0].w);
    u[4]  = f2b(t.f[1].x); u[5]  = f2b(t.f[1].y); u[6]  = f2b(t.f[1].z); u[7]  = f2b(t.f[1].w);
    u[8]  = f2b(t.f[2].x); u[9]  = f2b(t.f[2].y); u[10] = f2b(t.f[2].z); u[11] = f2b(t.f[2].w);
    u[12] = f2b(t.f[3].x); u[13] = f2b(t.f[3].y); u[14] = f2b(t.f[3].z); u[15] = f2b(t.f[3].w);
    ch0 = *(const bf16x8*)u; ch1 = *(const bf16x8*)(u + 8);
  } else { ch0 = t.h[0]; ch1 = t.h[1]; }
  const int swz = (row >> 1) & 3, c0 = half * 2;
  *(bf16x8*)(tile + row * 32 + (((c0    ) ^ swz) << 3)) = ch0;
  *(bf16x8*)(tile + row * 32 + (((c0 + 1) ^ swz) << 3)) = ch1;
}

// gate A tile [128 x 32] with 512 threads (tier-B fallback).
template <int DT> struct TRA { float4 f[2]; bf16x8 h; };

template <int DT>
__device__ __forceinline__ void ta_load(const void* gv, size_t base, int tid, TRA<DT>& t) {
  const int row = tid >> 2, g = tid & 3;
  const size_t off = base + (size_t)row * D_ + g * 8;
  if constexpr (DT == 0) {
    const float4* s = (const float4*)((const float*)gv + off);
    t.f[0] = s[0]; t.f[1] = s[1];
  } else {
    t.h = *(const bf16x8*)((const ushort_t*)gv + off);
  }
}
template <int DT>
__device__ __forceinline__ void ta_store(ushort_t* tile, int tid, const TRA<DT>& t) {
  const int row = tid >> 2, g = tid & 3;
  bf16x8 ch;
  if constexpr (DT == 0) {
    ushort_t u[8];
    u[0] = f2b(t.f[0].x); u[1] = f2b(t.f[0].y); u[2] = f2b(t.f[0].z); u[3] = f2b(t.f[0].w);
    u[4] = f2b(t.f[1].x); u[5] = f2b(t.f[1].y); u[6] = f2b(t.f[1].z); u[7] = f2b(t.f[1].w);
    ch = *(const bf16x8*)u;
  } else ch = t.h;
  const int swz = (row >> 1) & 3;
  *(bf16x8*)(tile + row * 32 + ((g ^ swz) << 3)) = ch;
}

// ---------------------------------------------------------------------------
// Weight pre-pass (unchanged): tiled pre-swizzled bf16 weights + f32 biases.
// ---------------------------------------------------------------------------
__global__ __launch_bounds__(256)
void convert_kernel(const void* __restrict__ shareW, const void* __restrict__ langsW,
                    const void* __restrict__ gW1, const void* __restrict__ gb1,
                    const void* __restrict__ gW2, const void* __restrict__ gb2,
                    const int* __restrict__ flag, char* __restrict__ ws) {
  const int t = blockIdx.x, tid = threadIdx.x;
  const int dt = flag[0];
  if (t < 1088) {
    const void* src; ushort_t* dst; size_t sb;
    if (t < 64) {
      src = shareW; dst = (ushort_t*)(ws + WS_SW) + (size_t)t * 4096;
      sb = ((size_t)(t >> 4) * 128) * D_ + (size_t)(t & 15) * 32;
    } else if (t < 576) {
      const int t2 = t - 64;
      src = langsW; dst = (ushort_t*)(ws + WS_LW) + (size_t)t2 * 4096;
      sb = ((size_t)(t2 >> 6) * 512 + (size_t)((t2 >> 4) & 3) * 128) * D_ + (size_t)(t2 & 15) * 32;
    } else {
      const int t3 = t - 576;
      src = gW1; dst = (ushort_t*)(ws + WS_W1) + (size_t)t3 * 4096;
      sb = ((size_t)(t3 >> 6) * 512 + (size_t)((t3 >> 4) & 3) * 128) * D_ + (size_t)(t3 & 15) * 32;
    }
    if (dt == 0) { TR16<0> r; t16_load<0>(src, sb, tid, r); t16_store<0>(dst, tid, r); }
    else         { TR16<1> r; t16_load<1>(src, sb, tid, r); t16_store<1>(dst, tid, r); }
  } else {
    float* b1f = (float*)(ws + WS_B1F);
    float* w2f = (float*)(ws + WS_W2F);
    float* b2w = (float*)(ws + WS_B2F);
    for (int i = tid; i < 4096; i += 256) {
      b1f[i] = dt ? b2f(((const ushort_t*)gb1)[i]) : ((const float*)gb1)[i];
      w2f[i] = dt ? b2f(((const ushort_t*)gW2)[i]) : ((const float*)gW2)[i];
    }
    if (tid < 8)
      b2w[tid] = dt ? b2f(((const ushort_t*)gb2)[tid]) : ((const float*)gb2)[tid];
  }
}

// ---------------------------------------------------------------------------
// x / old_x fp32 -> bf16 row-major streaming conversion (tier A, dt==0 only).
// ---------------------------------------------------------------------------
__global__ __launch_bounds__(256)
void xconv_kernel(const void* __restrict__ x, const void* __restrict__ oldx,
                  const int* __restrict__ flag, ushort_t* __restrict__ xb,
                  ushort_t* __restrict__ oxb) {
  if (flag[0] != 0) return;                    // bf16 inputs: read originals
  const long long N = (long long)B_ * S_ * D_ / 8;   // 4194304 chunks/array
  long long i = (long long)blockIdx.x * 256 + threadIdx.x;
  const long long stride = (long long)gridDim.x * 256;
  for (; i < 2 * N; i += stride) {
    const float4* s; ushort_t* d;
    if (i < N) { s = (const float4*)x    + i * 2;       d = xb  + i * 8; }
    else       { s = (const float4*)oldx + (i - N) * 2; d = oxb + (i - N) * 8; }
    float4 a = s[0], b = s[1];
    ushort_t u[8];
    u[0] = f2b(a.x); u[1] = f2b(a.y); u[2] = f2b(a.z); u[3] = f2b(a.w);
    u[4] = f2b(b.x); u[5] = f2b(b.y); u[6] = f2b(b.z); u[7] = f2b(b.w);
    *(bf16x8*)d = *(const bf16x8*)u;
  }
}

// ---------------------------------------------------------------------------
// TIER A kernels: all operands bf16, pure global_load_lds staging,
// raw s_barrier + counted vmcnt pipeline (3 bufs, depth-2 prefetch).
// ---------------------------------------------------------------------------
struct GateSmemA {
  alignas(16) ushort_t As[3][128 * 32];   // 24 KB
  alignas(16) ushort_t Bs[3][512 * 32];   // 96 KB
  float b1s[512], w2s[512], logit[128];   // 4.5 KB  -> 124.5 KB, 1 block/CU
};
struct OutSmemA {
  alignas(16) ushort_t As[3][128 * 32];   // 24 KB
  alignas(16) ushort_t Ss[3][128 * 32];   // 24 KB
  alignas(16) ushort_t Ls[3][128 * 32];   // 24 KB  -> 72 KB, 2 blocks/CU
};

__global__ __launch_bounds__(512, 2)
void gate_kernel_a(const void* __restrict__ old_x, const ushort_t* __restrict__ oxb,
                   const int* __restrict__ lang, const ushort_t* __restrict__ w1t,
                   const float* __restrict__ b1f, const float* __restrict__ w2f,
                   const float* __restrict__ b2w, const int* __restrict__ flag,
                   float* __restrict__ gate) {
  __shared__ GateSmemA sm;
  int bid = blockIdx.y * gridDim.x + blockIdx.x;            // 0..511
  int swz = (bid & 7) * 64 + (bid >> 3);                    // XCD-chunked
  const int s0 = (swz & 15) * 128;
  const int b  = swz >> 4;
  const int tid  = threadIdx.x;
  const int wave = tid >> 6, lane = tid & 63, quad = lane >> 4, ln = lane & 15;
  const int m_off = (wave >> 2) * 64;
  const int n_off = (wave & 3) * 128;
  const int lg = lang[b];
  const ushort_t* Abase = flag[0] ? (const ushort_t*)old_x : oxb;

  sm.b1s[tid] = b1f[lg * 512 + tid];
  sm.w2s[tid] = w2f[lg * 512 + tid];
  if (tid < 128) sm.logit[tid] = 0.f;
  __syncthreads();                        // biases visible before pipeline

  // A staging: wave stages slice `wave` (rows wave*16..+15) of [128x32] tile.
  // Swizzle baked into per-lane GLOBAL address; LDS dest linear.
  const int arow = wave * 16 + (lane >> 2);
  const int achk = (lane & 3) ^ ((arow >> 1) & 3);
  const ushort_t* asrc = Abase + ((size_t)(b * S_ + s0 + arow)) * D_ + achk * 8;

  const ushort_t* w1base = w1t + (size_t)lg * 64 * 4096;

  auto issue = [&](int kt, int buf) {       // 5 gloads per wave per step
    gload16(asrc + (size_t)kt * 32, (char*)sm.As[buf] + wave * 1024);
    #pragma unroll
    for (int c = 0; c < 4; ++c) {
      const int sl = c * 8 + wave, et = sl >> 3;
      gload16((const char*)(w1base + ((size_t)(et * 16 + kt)) * 4096)
                  + (sl & 7) * 1024 + lane * 16,
              (char*)sm.Bs[buf] + sl * 1024);
    }
  };

  f32x4 acc[4][8];
  #pragma unroll
  for (int i = 0; i < 4; ++i)
    #pragma unroll
    for (int j = 0; j < 8; ++j) { f32x4 z = {0.f, 0.f, 0.f, 0.f}; acc[i][j] = z; }

  issue(0, 0); issue(1, 1);                // depth-2 prologue (10 in flight)

  const int rrow  = tid >> 2, rg = tid & 3;
  const int rslot = (rg ^ ((rrow >> 1) & 3)) << 3;
  float res = 0.f;

  #pragma unroll
  for (int t = 0; t < 16; ++t) {
    if (t < 15) asm volatile("s_waitcnt vmcnt(5)" ::: "memory");  // own step-t done
    else        asm volatile("s_waitcnt vmcnt(0)" ::: "memory");
    __builtin_amdgcn_s_barrier();          // all waves' step-t tiles in LDS
    if (t + 2 < 16) issue(t + 2, (t + 2) % 3);   // loads stay in flight across barriers
    const ushort_t* Ab = sm.As[t % 3];
    const ushort_t* Bb = sm.Bs[t % 3];
    bf16x8 af[4];
    #pragma unroll
    for (int mf = 0; mf < 4; ++mf)
      af[mf] = read_frag(Ab, m_off + mf * 16 + ln, quad);
    {   // residual partial: sum_k old_x[s,k] * w2[k]
      bf16x8 rv = *(const bf16x8*)(Ab + rrow * 32 + rslot);
      #pragma unroll
      for (int j = 0; j < 8; ++j)
        res += b2f((ushort_t)rv[j]) * sm.w2s[t * 32 + rg * 8 + j];
    }
    #pragma unroll
    for (int nh = 0; nh < 2; ++nh) {
      bf16x8 bfr[4];
      #pragma unroll
      for (int nf = 0; nf < 4; ++nf)
        bfr[nf] = read_frag(Bb, n_off + (nh * 4 + nf) * 16 + ln, quad);
      #pragma unroll
      for (int mf = 0; mf < 4; ++mf)
        #pragma unroll
        for (int nf = 0; nf < 4; ++nf)
          acc[mf][nh * 4 + nf] = mfma16(af[mf], bfr[nf], acc[mf][nh * 4 + nf]);
    }
  }
  atomicAdd(&sm.logit[rrow], res);

  float logacc[16];
  #pragma unroll
  for (int i = 0; i < 16; ++i) logacc[i] = 0.f;
  #pragma unroll
  for (int nf = 0; nf < 8; ++nf) {
    int e = n_off + nf * 16 + ln;
    float b1v = sm.b1s[e], w2v = sm.w2s[e];
    #pragma unroll
    for (int mf = 0; mf < 4; ++mf)
      #pragma unroll
      for (int r = 0; r < 4; ++r) {
        float v = acc[mf][nf][r] + b1v;
        logacc[mf * 4 + r] += fmaxf(v, 0.f) * w2v;
      }
  }
  #pragma unroll
  for (int off = 1; off < 16; off <<= 1)
    #pragma unroll
    for (int i = 0; i < 16; ++i)
      logacc[i] += __shfl_xor(logacc[i], off, 64);
  if (ln == 0) {
    #pragma unroll
    for (int mf = 0; mf < 4; ++mf)
      #pragma unroll
      for (int r = 0; r < 4; ++r)
        atomicAdd(&sm.logit[m_off + mf * 16 + quad * 4 + r], logacc[mf * 4 + r]);
  }
  __syncthreads();
  if (tid < 128) {
    float l = sm.logit[tid] + b2w[lg];
    gate[(size_t)b * S_ + s0 + tid] = 1.f / (1.f + expf(-l));
  }
}

__global__ __launch_bounds__(256, 2)
void out_kernel_a(const void* __restrict__ x, const ushort_t* __restrict__ xb,
                  const int* __restrict__ lang, const ushort_t* __restrict__ sWt,
                  const ushort_t* __restrict__ lWt, const float* __restrict__ gate,
                  const int* __restrict__ flag, void* __restrict__ out) {
  __shared__ OutSmemA sm;
  int bid = (blockIdx.z * gridDim.y + blockIdx.y) * gridDim.x + blockIdx.x;
  int swz = (bid & 7) * 256 + (bid >> 3);                  // XCD-chunked
  const int eb = swz & 3, e0 = eb * 128;
  const int s0 = ((swz >> 2) & 15) * 128;
  const int b  = swz >> 6;
  const int tid  = threadIdx.x;
  const int wave = tid >> 6, lane = tid & 63, quad = lane >> 4, ln = lane & 15;
  const int m_off = (wave >> 1) * 64, n_off = (wave & 1) * 64;
  const int lg = lang[b];
  const int dt = flag[0];
  const ushort_t* Abase = dt ? (const ushort_t*)x : xb;

  const ushort_t* Sbase = sWt + (size_t)eb * 16 * 4096;
  const ushort_t* Lbase = lWt + ((size_t)(lg * 4 + eb)) * 16 * 4096;

  // A: 2 slices per wave (sl = c*4+wave), pre-swizzled global source.
  const ushort_t* asrc[2];
  #pragma unroll
  for (int c = 0; c < 2; ++c) {
    const int sl = c * 4 + wave;
    const int arow = sl * 16 + (lane >> 2);
    const int achk = (lane & 3) ^ ((arow >> 1) & 3);
    asrc[c] = Abase + ((size_t)(b * S_ + s0 + arow)) * D_ + achk * 8;
  }

  auto issue = [&](int kt, int buf) {       // 6 gloads per wave per step
    #pragma unroll
    for (int c = 0; c < 2; ++c) {
      const int sl = c * 4 + wave;
      gload16(asrc[c] + (size_t)kt * 32, (char*)sm.As[buf] + sl * 1024);
    }
    #pragma unroll
    for (int c = 0; c < 2; ++c) {
      const int sl = c * 4 + wave;
      const int boff = sl * 1024 + lane * 16;
      gload16((const char*)(Sbase + (size_t)kt * 4096) + boff,
              (char*)sm.Ss[buf] + sl * 1024);
      gload16((const char*)(Lbase + (size_t)kt * 4096) + boff,
              (char*)sm.Ls[buf] + sl * 1024);
    }
  };

  f32x4 accS[4][4], accL[4][4];
  #pragma unroll
  for (int i = 0; i < 4; ++i)
    #pragma unroll
    for (int j = 0; j < 4; ++j) {
      f32x4 z = {0.f, 0.f, 0.f, 0.f};
      accS[i][j] = z; accL[i][j] = z;
    }

  issue(0, 0); issue(1, 1);                // depth-2 prologue (12 in flight)

  #pragma unroll
  for (int t = 0; t < 16; ++t) {
    if (t < 15) asm volatile("s_waitcnt vmcnt(6)" ::: "memory");
    else        asm volatile("s_waitcnt vmcnt(0)" ::: "memory");
    __builtin_amdgcn_s_barrier();
    if (t + 2 < 16) issue(t + 2, (t + 2) % 3);
    const ushort_t* Ab = sm.As[t % 3];
    const ushort_t* Sb = sm.Ss[t % 3];
    const ushort_t* Lb = sm.Ls[t % 3];
    bf16x8 af[4], sf[4], lf[4];
    #pragma unroll
    for (int mf = 0; mf < 4; ++mf)
      af[mf] = read_frag(Ab, m_off + mf * 16 + ln, quad);
    #pragma unroll
    for (int nf = 0; nf < 4; ++nf) {
      sf[nf] = read_frag(Sb, n_off + nf * 16 + ln, quad);
      lf[nf] = read_frag(Lb, n_off + nf * 16 + ln, quad);
    }
    #pragma unroll
    for (int mf = 0; mf < 4; ++mf)
      #pragma unroll
      for (int nf = 0; nf < 4; ++nf) {
        accS[mf][nf] = mfma16(af[mf], sf[nf], accS[mf][nf]);
        accL[mf][nf] = mfma16(af[mf], lf[nf], accL[mf][nf]);
      }
  }

  // epilogue: blend with gate, plain stores.
  #pragma unroll
  for (int mf = 0; mf < 4; ++mf) {
    int srow = s0 + m_off + mf * 16 + quad * 4;
    float4 gv = *(const float4*)&gate[(size_t)b * S_ + srow];
    #pragma unroll
    for (int nf = 0; nf < 4; ++nf) {
      int col = e0 + n_off + nf * 16 + ln;
      f32x4 cs = accS[mf][nf], cl = accL[mf][nf];
      float gr[4] = {gv.x, gv.y, gv.z, gv.w};
      #pragma unroll
      for (int r = 0; r < 4; ++r) {
        float v = cs[r] + gr[r] * (cl[r] - cs[r]);
        size_t idx = ((size_t)b * S_ + srow + r) * D_ + col;
        if (dt == 0) ((float*)out)[idx] = v;
        else         ((ushort_t*)out)[idx] = f2b(v);
      }
    }
  }
}

// ---------------------------------------------------------------------------
// TIER B fallback (Round-4 kernels, used when workspace too small).
// ---------------------------------------------------------------------------
struct GateSmem {
  alignas(16) ushort_t As[2][128 * 32];
  alignas(16) ushort_t Bs[2][512 * 32];
  float b1s[512], w2s[512], logit[128];
};
struct OutSmem {
  alignas(16) ushort_t As[2][128 * 32];
  alignas(16) ushort_t Ss[2][128 * 32];
  alignas(16) ushort_t Ls[2][128 * 32];
};

template <int DT>
__device__ __forceinline__ void gate_body(const void* __restrict__ old_x,
    const int* __restrict__ lang, const ushort_t* __restrict__ w1t,
    const float* __restrict__ b1f, const float* __restrict__ w2f,
    const float* __restrict__ b2w, float* __restrict__ gate, GateSmem& sm) {
  int bid = blockIdx.y * gridDim.x + blockIdx.x;
  int swz = (bid & 7) * 64 + (bid >> 3);
  const int s0 = (swz & 15) * 128;
  const int b  = swz >> 4;
  const int tid  = threadIdx.x;
  const int wave = tid >> 6, lane = tid & 63, quad = lane >> 4, ln = lane & 15;
  const int m_off = (wave >> 2) * 64;
  const int n_off = (wave & 3) * 128;
  const int lg = lang[b];

  sm.b1s[tid] = b1f[lg * 512 + tid];
  sm.w2s[tid] = w2f[lg * 512 + tid];
  if (tid < 128) sm.logit[tid] = 0.f;

  const size_t Aoff = ((size_t)b * S_ + s0) * D_;
  const ushort_t* w1base = w1t + (size_t)lg * 64 * 4096;

  auto stageB = [&](int kt, int buf) {
    #pragma unroll
    for (int c = 0; c < 4; ++c) {
      const int sl = c * 8 + wave;
      const int et = sl >> 3;
      const char* g = (const char*)(w1base + ((size_t)(et * 16 + kt)) * 4096)
                      + (sl & 7) * 1024 + lane * 16;
      gload16(g, (char*)sm.Bs[buf] + sl * 1024);
    }
  };

  f32x4 acc[4][8];
  #pragma unroll
  for (int i = 0; i < 4; ++i)
    #pragma unroll
    for (int j = 0; j < 8; ++j) { f32x4 z = {0.f, 0.f, 0.f, 0.f}; acc[i][j] = z; }

  TRA<DT> ta;
  stageB(0, 0);
  ta_load<DT>(old_x, Aoff, tid, ta);
  ta_store<DT>(sm.As[0], tid, ta);
  __syncthreads();

  const int rrow  = tid >> 2, rg = tid & 3;
  const int rslot = (rg ^ ((rrow >> 1) & 3)) << 3;
  float res = 0.f;

  for (int step = 0; step < 16; ++step) {
    const int cur = step & 1;
    if (step < 15) {
      stageB(step + 1, cur ^ 1);
      ta_load<DT>(old_x, Aoff + (step + 1) * 32, tid, ta);
    }
    bf16x8 af[4];
    #pragma unroll
    for (int mf = 0; mf < 4; ++mf)
      af[mf] = read_frag(sm.As[cur], m_off + mf * 16 + ln, quad);
    {
      bf16x8 rv = *(const bf16x8*)(sm.As[cur] + rrow * 32 + rslot);
      #pragma unroll
      for (int j = 0; j < 8; ++j)
        res += b2f((ushort_t)rv[j]) * sm.w2s[step * 32 + rg * 8 + j];
    }
    #pragma unroll
    for (int nh = 0; nh < 2; ++nh) {
      bf16x8 bfr[4];
      #pragma unroll
      for (int nf = 0; nf < 4; ++nf)
        bfr[nf] = read_frag(sm.Bs[cur], n_off + (nh * 4 + nf) * 16 + ln, quad);
      #pragma unroll
      for (int mf = 0; mf < 4; ++mf)
        #pragma unroll
        for (int nf = 0; nf < 4; ++nf)
          acc[mf][nh * 4 + nf] = mfma16(af[mf], bfr[nf], acc[mf][nh * 4 + nf]);
    }
    if (step < 15) ta_store<DT>(sm.As[cur ^ 1], tid, ta);
    __syncthreads();
  }
  atomicAdd(&sm.logit[rrow], res);

  float logacc[16];
  #pragma unroll
  for (int i = 0; i < 16; ++i) logacc[i] = 0.f;
  #pragma unroll
  for (int nf = 0; nf < 8; ++nf) {
    int e = n_off + nf * 16 + ln;
    float b1v = sm.b1s[e], w2v = sm.w2s[e];
    #pragma unroll
    for (int mf = 0; mf < 4; ++mf)
      #pragma unroll
      for (int r = 0; r < 4; ++r) {
        float v = acc[mf][nf][r] + b1v;
        logacc[mf * 4 + r] += fmaxf(v, 0.f) * w2v;
      }
  }
  #pragma unroll
  for (int off = 1; off < 16; off <<= 1)
    #pragma unroll
    for (int i = 0; i < 16; ++i)
      logacc[i] += __shfl_xor(logacc[i], off, 64);
  if (ln == 0) {
    #pragma unroll
    for (int mf = 0; mf < 4; ++mf)
      #pragma unroll
      for (int r = 0; r < 4; ++r)
        atomicAdd(&sm.logit[m_off + mf * 16 + quad * 4 + r], logacc[mf * 4 + r]);
  }
  __syncthreads();
  if (tid < 128) {
    float l = sm.logit[tid] + b2w[lg];
    gate[(size_t)b * S_ + s0 + tid] = 1.f / (1.f + expf(-l));
  }
}

__global__ __launch_bounds__(512, 2)
void gate_kernel(const void* __restrict__ old_x, const int* __restrict__ lang,
                 const ushort_t* __restrict__ w1t, const float* __restrict__ b1f,
                 const float* __restrict__ w2f, const float* __restrict__ b2w,
                 const int* __restrict__ flag, float* __restrict__ gate) {
  __shared__ GateSmem sm;
  if (flag[0] == 0) gate_body<0>(old_x, lang, w1t, b1f, w2f, b2w, gate, sm);
  else              gate_body<1>(old_x, lang, w1t, b1f, w2f, b2w, gate, sm);
}

template <int DT>
__device__ __forceinline__ void out_body(const void* __restrict__ x,
    const int* __restrict__ lang, const ushort_t* __restrict__ sWt,
    const ushort_t* __restrict__ lWt, const float* __restrict__ gate,
    void* __restrict__ out, OutSmem& sm) {
  int bid = (blockIdx.z * gridDim.y + blockIdx.y) * gridDim.x + blockIdx.x;
  int swz = (bid & 7) * 256 + (bid >> 3);
  const int eb = swz & 3, e0 = eb * 128;
  const int s0 = ((swz >> 2) & 15) * 128;
  const int b  = swz >> 6;
  const int tid  = threadIdx.x;
  const int wave = tid >> 6, lane = tid & 63, quad = lane >> 4, ln = lane & 15;
  const int m_off = (wave >> 1) * 64, n_off = (wave & 1) * 64;
  const int lg = lang[b];

  const size_t Aoff = ((size_t)b * S_ + s0) * D_;
  const ushort_t* Sbase = sWt + (size_t)eb * 16 * 4096;
  const ushort_t* Lbase = lWt + ((size_t)(lg * 4 + eb)) * 16 * 4096;

  auto stageSL = [&](int kt, int buf) {
    #pragma unroll
    for (int c = 0; c < 2; ++c) {
      const int sl = c * 4 + wave;
      const int boff = sl * 1024 + lane * 16;
      gload16((const char*)(Sbase + (size_t)kt * 4096) + boff,
              (char*)sm.Ss[buf] + sl * 1024);
      gload16((const char*)(Lbase + (size_t)kt * 4096) + boff,
              (char*)sm.Ls[buf] + sl * 1024);
    }
  };

  f32x4 accS[4][4], accL[4][4];
  #pragma unroll
  for (int i = 0; i < 4; ++i)
    #pragma unroll
    for (int j = 0; j < 4; ++j) {
      f32x4 z = {0.f, 0.f, 0.f, 0.f};
      accS[i][j] = z; accL[i][j] = z;
    }

  TR16<DT> ta;
  stageSL(0, 0);
  t16_load<DT>(x, Aoff, tid, ta);
  t16_store<DT>(sm.As[0], tid, ta);
  __syncthreads();

  for (int step = 0; step < 16; ++step) {
    const int cur = step & 1;
    if (step < 15) {
      stageSL(step + 1, cur ^ 1);
      t16_load<DT>(x, Aoff + (step + 1) * 32, tid, ta);
    }
    bf16x8 af[4], sf[4], lf[4];
    #pragma unroll
    for (int mf = 0; mf < 4; ++mf)
      af[mf] = read_frag(sm.As[cur], m_off + mf * 16 + ln, quad);
    #pragma unroll
    for (int nf = 0; nf < 4; ++nf) {
      sf[nf] = read_frag(sm.Ss[cur], n_off + nf * 16 + ln, quad);
      lf[nf] = read_frag(sm.Ls[cur], n_off + nf * 16 + ln, quad);
    }
    #pragma unroll
    for (int mf = 0; mf < 4; ++mf)
      #pragma unroll
      for (int nf = 0; nf < 4; ++nf) {
        accS[mf][nf] = mfma16(af[mf], sf[nf], accS[mf][nf]);
        accL[mf][nf] = mfma16(af[mf], lf[nf], accL[mf][nf]);
      }
    if (step < 15) t16_store<DT>(sm.As[cur ^ 1], tid, ta);
    __syncthreads();
  }

  #pragma unroll
  for (int mf = 0; mf < 4; ++mf) {
    int srow = s0 + m_off + mf * 16 + quad * 4;
    float gv[4];
    #pragma unroll
    for (int r = 0; r < 4; ++r) gv[r] = gate[(size_t)b * S_ + srow + r];
    #pragma unroll
    for (int nf = 0; nf < 4; ++nf) {
      int col = e0 + n_off + nf * 16 + ln;
      f32x4 cs = accS[mf][nf], cl = accL[mf][nf];
      #pragma unroll
      for (int r = 0; r < 4; ++r) {
        float v = cs[r] + gv[r] * (cl[r] - cs[r]);
        size_t idx = ((size_t)b * S_ + srow + r) * D_ + col;
        if constexpr (DT == 0) ((float*)out)[idx] = v;
        else                   ((ushort_t*)out)[idx] = f2b(v);
      }
    }
  }
}

__global__ __launch_bounds__(256, 2)
void out_kernel(const void* __restrict__ x, const int* __restrict__ lang,
                const ushort_t* __restrict__ sWt, const ushort_t* __restrict__ lWt,
                const float* __restrict__ gate, const int* __restrict__ flag,
                void* __restrict__ out) {
  __shared__ OutSmem sm;
  if (flag[0] == 0) out_body<0>(x, lang, sWt, lWt, gate, out, sm);
  else              out_body<1>(x, lang, sWt, lWt, gate, out, sm);
}

extern "C" void kernel_launch(void* const* d_in, const int* in_sizes, int n_in,
                              void* d_out, int out_size, void* d_ws, size_t ws_size,
                              hipStream_t stream) {
  const void* old_x  = d_in[0];
  const void* x      = d_in[1];
  const int*  lang   = (const int*)d_in[2];
  const void* shareW = d_in[3];
  const void* langsW = d_in[4];
  const void* gW1    = d_in[5];
  const void* gb1    = d_in[6];
  const void* gW2    = d_in[7];
  const void* gb2    = d_in[8];

  char*  ws   = (char*)d_ws;
  float* gate = (float*)(ws + WS_GATE);
  int*   flag = (int*)(ws + WS_FLAG);
  const ushort_t* sWt = (const ushort_t*)(ws + WS_SW);
  const ushort_t* lWt = (const ushort_t*)(ws + WS_LW);
  const ushort_t* w1t = (const ushort_t*)(ws + WS_W1);
  const float*    b1f = (const float*)(ws + WS_B1F);
  const float*    w2f = (const float*)(ws + WS_W2F);
  const float*    b2w = (const float*)(ws + WS_B2F);
  ushort_t* xb  = (ushort_t*)(ws + WS_XB);
  ushort_t* oxb = (ushort_t*)(ws + WS_OXB);

  const bool tierA = ws_size >= (size_t)WS_NEED;

  detect_kernel<<<1, 256, 0, stream>>>((const unsigned int*)old_x, flag);
  convert_kernel<<<1089, 256, 0, stream>>>(shareW, langsW, gW1, gb1, gW2, gb2,
                                           flag, ws);

  dim3 g1(S_ / 128, B_);
  dim3 g2(D_ / 128, S_ / 128, B_);
  if (tierA) {
    xconv_kernel<<<3072, 256, 0, stream>>>(x, old_x, flag, xb, oxb);
    gate_kernel_a<<<g1, dim3(512), 0, stream>>>(old_x, oxb, lang, w1t, b1f, w2f,
                                                b2w, flag, gate);
    out_kernel_a<<<g2, dim3(256), 0, stream>>>(x, xb, lang, sWt, lWt, gate,
                                               flag, d_out);
  } else {
    gate_kernel<<<g1, dim3(512), 0, stream>>>(old_x, lang, w1t, b1f, w2f, b2w,
                                              flag, gate);
    out_kernel<<<g2, dim3(256), 0, stream>>>(x, lang, sWt, lWt, gate, flag, d_out);
  }
}